// Round 1
// baseline (4838.285 us; speedup 1.0000x reference)
//
#include <hip/hip_runtime.h>
#include <stdint.h>

#define V 4096
#define D 128
#define E 12288
#define NPAD 16384
#define HALF 8192
#define TARGET 2048

// ws layout (bytes)
#define WS_N     0u                       // V*V uint8      = 16777216
#define WS_PRI   16777216u                // V float        = 16384
#define WS_KEYS  (16777216u + 16384u)     // NPAD u64       = 131072
#define WS_ALIVE (16777216u + 16384u + 131072u)  // V uint8

__global__ void k_scatter(const int* __restrict__ edges, uint8_t* __restrict__ n) {
    int e = blockIdx.x * 256 + threadIdx.x;
    if (e < E) {
        int a = edges[e], b = edges[E + e];
        n[a * V + b] = 2;
        n[b * V + a] = 2;
    }
}

// numpy pairwise f32 sum for n=128: 8 strided accumulators, then
// ((r0+r1)+(r2+r3)) + ((r4+r5)+(r6+r7)). No FMA contraction.
__global__ void k_pri(const float* __restrict__ f, float* __restrict__ pri) {
    int v = blockIdx.x * 256 + threadIdx.x;
    if (v < V) {
        const float* p = f + v * D;
        float r[8];
#pragma unroll
        for (int j = 0; j < 8; j++) r[j] = __fmul_rn(p[j], p[j]);
        for (int i = 8; i < D; i += 8) {
#pragma unroll
            for (int j = 0; j < 8; j++)
                r[j] = __fadd_rn(r[j], __fmul_rn(p[i + j], p[i + j]));
        }
        float s01 = __fadd_rn(r[0], r[1]);
        float s23 = __fadd_rn(r[2], r[3]);
        float s45 = __fadd_rn(r[4], r[5]);
        float s67 = __fadd_rn(r[6], r[7]);
        pri[v] = __fadd_rn(__fadd_rn(s01, s23), __fadd_rn(s45, s67));
    }
}

__global__ void k_copy(const float* __restrict__ f, float* __restrict__ out) {
    int i = blockIdx.x * 256 + threadIdx.x;
    if (i < V * D) out[i] = f[i];
}

__global__ void k_mask(const uint8_t* __restrict__ aliveG, float* __restrict__ out) {
    int i = blockIdx.x * 256 + threadIdx.x;
    if (i < V * D) {
        if (!aliveG[i >> 7]) out[i] = 0.0f;
    }
}

__launch_bounds__(256)
__global__ void k_main(const int* __restrict__ edges, const float* __restrict__ priG,
                       uint8_t* __restrict__ n, unsigned long long* __restrict__ keys,
                       uint8_t* __restrict__ aliveG, float* __restrict__ out) {
    __shared__ union {
        unsigned long long srt[HALF];        // 64 KB (bitonic buffer)
        struct {
            unsigned pk[E];                  // 48 KB packed (v0<<16|v1) in sorted order
            uint8_t alive[V];                // 4 KB
        } g;
    } sh;
    const int tid = threadIdx.x;

    // ---- phase 1: build u64 keys = (bits(epri) << 32) | idx ; pads sort last ----
    for (int s = tid; s < NPAD; s += 256) {
        unsigned long long rec;
        if (s < E) {
            int a = edges[s], b = edges[E + s];
            float k = __fadd_rn(priG[a], priG[b]);   // epri >= 0 -> bits are monotone
            rec = ((unsigned long long)__float_as_uint(k) << 32) | (unsigned)s;
        } else {
            rec = (0xFFFFFFFFull << 32) | (unsigned)s;
        }
        keys[s] = rec;
    }
    __syncthreads();

    // ---- phase 2: bitonic sort each 8192 half in LDS (u64 keys are unique => stable) ----
    for (int h = 0; h < 2; h++) {
        unsigned long long* base = keys + h * HALF;
        for (int s = tid; s < HALF; s += 256) sh.srt[s] = base[s];
        __syncthreads();
        for (int k = 2; k <= HALF; k <<= 1) {
            for (int j = k >> 1; j >= 1; j >>= 1) {
                for (int i = tid; i < HALF; i += 256) {
                    int ixj = i ^ j;
                    if (ixj > i) {
                        unsigned long long a = sh.srt[i], b = sh.srt[ixj];
                        bool up = ((i & k) == 0);
                        if ((a > b) == up) { sh.srt[i] = b; sh.srt[ixj] = a; }
                    }
                }
                __syncthreads();
            }
        }
        for (int s = tid; s < HALF; s += 256) base[s] = sh.srt[s];
        __syncthreads();
    }

    // ---- phase 3: merge-path the two sorted halves -> sh.g.pk[0..E) ----
    {
        const unsigned long long* A = keys;
        const unsigned long long* B = keys + HALF;
        for (int t = tid; t < (E / 64); t += 256) {  // 192 segments of 64 outputs
            int d = t * 64;
            int lo = d > HALF ? d - HALF : 0;
            int hi = d < HALF ? d : HALF;
            while (lo < hi) {
                int mid = (lo + hi) >> 1;
                if (A[mid] < B[d - 1 - mid]) lo = mid + 1; else hi = mid;
            }
            int ia = lo, ib = d - lo;
            int end = d + 64; if (end > E) end = E;
            for (int o = d; o < end; o++) {
                bool takeA = (ib >= HALF) || (ia < HALF && A[ia] < B[ib]);
                unsigned long long r = takeA ? A[ia++] : B[ib++];
                int e = (int)(r & 0xFFFFFFFFull);
                int a = edges[e], b = edges[E + e];
                sh.g.pk[o] = ((unsigned)a << 16) | (unsigned)b;
            }
        }
        for (int v = tid; v < V; v += 256) sh.g.alive[v] = 1;
    }
    __syncthreads();

    // ---- phase 4: greedy collapse, ONE wave (lockstep, no barriers needed) ----
    if (tid < 64) {
        const int lane = tid;
        int cnt = V;
        for (int e = 0; e < E; e++) {
            unsigned p = sh.g.pk[e];
            int v0 = (int)(p >> 16), v1 = (int)(p & 0xFFFFu);
            if (!sh.g.alive[v0] || !sh.g.alive[v1]) continue;
            if (n[v0 * V + v1] != 2) continue;

            // f_acc[v0] = 0.5*(f_acc[v0]+f_acc[v1]) : 128 floats = 64 lanes x float2
            {
                float2* fa = (float2*)(out + v0 * D);
                float2* fb = (float2*)(out + v1 * D);
                float2 a = fa[lane], b = fb[lane];
                fa[lane] = make_float2(0.5f * (a.x + b.x), 0.5f * (a.y + b.y));
            }

            // neighbor row merge with per-byte saturate-at-3 (==2 predicate exact)
            uint32_t* rA = (uint32_t*)(n + (size_t)v0 * V);
            uint32_t* rB = (uint32_t*)(n + (size_t)v1 * V);
#pragma unroll
            for (int it = 0; it < 4; it++) {
                int c = it * 64 + lane;      // u32 chunk index, bytes [c*4, c*4+4)
                uint32_t a = rA[c], b = rB[c];
                uint32_t x = a + b;                        // bytes <= 6, no carry
                uint32_t hh = (x >> 2) & 0x01010101u;      // byte >= 4 ?
                uint32_t full = hh * 255u;                 // 0xFF where >=4
                uint32_t r = (x & ~full) | (0x03030303u & full);
                int base = c * 4;
                if (v0 >= base && v0 < base + 4) r &= ~(0xFFu << ((v0 - base) * 8));
                if (v1 >= base && v1 < base + 4) r &= ~(0xFFu << ((v1 - base) * 8));
                rA[c] = r;
                rB[c] = 0;
                // symmetric column fixups only where row v1 had a nonzero byte
                if (b) {
#pragma unroll
                    for (int q = 0; q < 4; q++) {
                        if ((b >> (q * 8)) & 0xFFu) {
                            int xv = base + q;
                            n[(size_t)xv * V + v0] = (uint8_t)((r >> (q * 8)) & 0xFFu);
                            n[(size_t)xv * V + v1] = 0;
                        }
                    }
                }
            }
            if (lane == 0) sh.g.alive[v1] = 0;
            cnt--;
            if (cnt == TARGET) break;   // no further state change possible
        }
        // outputs: alive (float) + cnt (float) + alive bytes for k_mask
        for (int v = lane; v < V; v += 64) {
            uint8_t a = sh.g.alive[v];
            aliveG[v] = a;
            out[V * D + v] = a ? 1.0f : 0.0f;
        }
        if (lane == 0) out[V * D + V] = (float)cnt;
    }
}

extern "C" void kernel_launch(void* const* d_in, const int* in_sizes, int n_in,
                              void* d_out, int out_size, void* d_ws, size_t ws_size,
                              hipStream_t stream) {
    (void)in_sizes; (void)n_in; (void)out_size; (void)ws_size;
    const float* features = (const float*)d_in[0];
    const int* edges = (const int*)d_in[1];
    uint8_t* ws = (uint8_t*)d_ws;
    uint8_t* nmat = ws + WS_N;
    float* pri = (float*)(ws + WS_PRI);
    unsigned long long* keys = (unsigned long long*)(ws + WS_KEYS);
    uint8_t* aliveG = ws + WS_ALIVE;
    float* out = (float*)d_out;

    hipMemsetAsync(nmat, 0, (size_t)V * V, stream);
    k_scatter<<<(E + 255) / 256, 256, 0, stream>>>(edges, nmat);
    k_pri<<<(V + 255) / 256, 256, 0, stream>>>(features, pri);
    k_copy<<<(V * D + 255) / 256, 256, 0, stream>>>(features, out);
    k_main<<<1, 256, 0, stream>>>(edges, pri, nmat, keys, aliveG, out);
    k_mask<<<(V * D + 255) / 256, 256, 0, stream>>>(aliveG, out);
}